// Round 11
// baseline (60.793 us; speedup 1.0000x reference)
//
#include <hip/hip_runtime.h>
#include <hip/hip_bf16.h>
#include <math.h>

#define NN 4096
// (1/64) * log2(e)  -- folds 1/sqrt(N) and exp->exp2 conversion
#define SCL 0.022542110013890054f
#define LOG2E 1.4426950408889634f

typedef __attribute__((ext_vector_type(8))) short bf16x8;
typedef __attribute__((ext_vector_type(4))) float f32x4;
typedef __attribute__((ext_vector_type(4))) short s16x4;

__device__ __forceinline__ float exp2_fast(float x) {
  float r; asm("v_exp_f32 %0, %1" : "=v"(r) : "v"(x)); return r;
}
__device__ __forceinline__ short bf16s(float x) {
  __hip_bfloat16 b = __float2bfloat16(x);
  return *(short*)&b;
}
__device__ __forceinline__ float bf2f(unsigned short u) {
  unsigned v = (unsigned)u << 16; return *(float*)&v;
}
__device__ __forceinline__ void gload16(const void* g, void* l) {
  __builtin_amdgcn_global_load_lds(
      (const __attribute__((address_space(1))) unsigned*)g,
      (__attribute__((address_space(3))) unsigned*)l, 16, 0, 0);
}

// ---------------------------------------------------------------------------
// Kernel 1 (fused by block range):
//   blocks [0,2048):    Wh = h@W -> fragment-major WhTf; E-tables (validated).
//   blocks [2048,2560): adj -> bits[i][g] via coalesced dword-ballot:
//     lane = j (256 B/instr coalesced reads, HBM rate); 32 ballots/half-row;
//     lane l latches word l (k = l>>1, half = l&1) via cndmask; one coalesced
//     256-B store per half-row. Bit semantics unchanged: word g covers
//     j in [32g, 32g+32), bit = j&31.
// ---------------------------------------------------------------------------
__global__ __launch_bounds__(256)
void k_prep(const float* __restrict__ h, const float* __restrict__ W,
            const float* __restrict__ a, const int* __restrict__ adj,
            unsigned short* __restrict__ WhTf, float2* __restrict__ Eit,
            float2* __restrict__ Ejt, unsigned* __restrict__ bits) {
  const int t = threadIdx.x;
  const int bi = blockIdx.x;
  if (bi >= 2048) {
    const int w = t >> 6, lane = t & 63;
    const int aw = (bi - 2048) * 4 + w;          // wave -> 2 rows
    const int kq = lane >> 1, hi = lane & 1;
#pragma unroll
    for (int half = 0; half < 4; ++half) {
      const int r = aw * 2 + (half >> 1);
      const int* __restrict__ src = adj + ((size_t)r << 12) + (half & 1) * 2048;
      unsigned myw = 0;
      for (int k = 0; k < 32; ++k) {
        unsigned long long m = __ballot(src[k * 64 + lane] != 0);
        unsigned lohi = hi ? (unsigned)(m >> 32) : (unsigned)m;
        myw = (kq == k) ? lohi : myw;
      }
      bits[((size_t)r << 7) + (half & 1) * 64 + lane] = myw;
    }
    return;
  }
  // ---- Wh path: 8 rows (same batch) per block ----
  __shared__ float sW[4096];
  __shared__ unsigned short T[64][8];
#pragma unroll
  for (int i = 0; i < 16; ++i) sW[i * 256 + t] = W[i * 256 + t];
  __syncthreads();
  const int wv = t >> 6, lane = t & 63;
  const float a1 = a[lane], a2 = a[64 + lane];
  const int row0 = bi * 8;
  for (int r = 0; r < 2; ++r) {
    const int row = row0 + wv * 2 + r;
    const float* hr = h + (size_t)row * 64;
    float acc = 0.f;
#pragma unroll
    for (int k = 0; k < 64; ++k) acc = fmaf(hr[k], sW[k * 64 + lane], acc);
    T[lane][wv * 2 + r] = (unsigned short)bf16s(acc);
    float r1 = acc * a1, r2 = acc * a2;
#pragma unroll
    for (int sft = 32; sft; sft >>= 1) { r1 += __shfl_xor(r1, sft); r2 += __shfl_xor(r2, sft); }
    if (lane == 0) {
      const float w1s = r1 * SCL, w2s = r2 * SCL;
      Eit[row] = make_float2(exp2_fast(w1s), exp2_fast(0.2f * w1s));
      Ejt[row] = make_float2(exp2_fast(w2s), exp2_fast(0.2f * w2s));
    }
  }
  __syncthreads();
  // fragment-major store (validated): (b, ft, g, lane=rg*16+jp, e) holds
  // Wh[n = g*32 + rg*8 + e][f = ft*16 + jp].
  const int f = t >> 2, jp4 = t & 3;
  const int b = row0 >> 12, n0 = row0 & 4095;
  const int g32 = n0 >> 5, rgq = (n0 >> 3) & 3;
  unsigned v = *(unsigned*)&T[f][jp4 * 2];
  unsigned short* dst = WhTf +
      ((((size_t)(b * 4 + (f >> 4)) << 7) + g32) << 9) +
      ((rgq * 16 + (f & 15)) << 3) + jp4 * 2;
  *(unsigned*)dst = v;
}

// ---------------------------------------------------------------------------
// Kernel 2: masked-softmax attention partials via MFMA, super-window pipeline.
// Grid 1024 = 4 chunks x 4 b x 64 i-blocks (64 rows). Block 256 thr = 4
// waves; wave w owns i-rows [i0+16w,+16) and stages fragment ft=w.
// SUPER-WINDOW: 4 windows (128 j) per barrier -> 8 barriers total.
// Ring: 2 slots x 16 KB. Per super s: [vmcnt(0) (stage(s) landed long ago);
// s_barrier; issue stage(s+1) (post-barrier => race-free with 2 slots);
// 4x window compute with NO fences: ds_read af, global-L1 ej, LDS mask,
// p = adj ? max(E1i*E1j, E2i*E2j) : 0 (exact), 5 MFMA].
// LDS = 32 KB ring + 8 KB transposed mask = 40 KB -> 4 blocks/CU.
// ---------------------------------------------------------------------------
__global__ __launch_bounds__(256, 4)
void k_gat(const unsigned* __restrict__ bits,
           const unsigned short* __restrict__ WhTf,
           const float2* __restrict__ Eit, const float* __restrict__ Ejt,
           unsigned short* __restrict__ Pp, float* __restrict__ lsp) {
  __shared__ unsigned short abuf[2][4][4][512];  // [slot][win][ft][lane*8] 32 KB
  __shared__ unsigned mldsT[32][64];             // [win][row] 8 KB

  const int t = threadIdx.x;
  const int w = t >> 6, lane = t & 63;
  const int jp = lane & 15, rg = lane >> 4;
  const int bid = blockIdx.x;
  const int c = bid >> 8;
  const int b = (bid >> 6) & 3;
  const int i0 = (bid & 63) * 64;
  const int g0 = c * 32;

  // one-time: mask rows -> transposed LDS [win][row]
  {
    const int row = t >> 2;
    const unsigned* src = bits + ((size_t)(i0 + row) << 7) + g0;
#pragma unroll
    for (int g = (t & 3); g < 32; g += 4) mldsT[g][row] = src[g];
  }
  // prologue: stage super 0 into slot 0 (wave w stages ft=w, 4 windows)
  const size_t fbase = ((size_t)(b * 4 + w) << 7) + g0;
#pragma unroll
  for (int wi = 0; wi < 4; ++wi)
    gload16(WhTf + ((fbase + wi) << 9) + lane * 8, &abuf[0][wi][w][lane * 8]);

  const float2 ei = Eit[b * NN + i0 + w * 16 + jp];
  const float E1i = ei.x, E2i = ei.y;
  const float* __restrict__ ejbase =
      Ejt + ((size_t)b * NN + (size_t)g0 * 32) * 2 + rg * 16;

  f32x4 acc[4];
#pragma unroll
  for (int ft = 0; ft < 4; ++ft) acc[ft] = (f32x4){0.f, 0.f, 0.f, 0.f};
  f32x4 accd = (f32x4){0.f, 0.f, 0.f, 0.f};
  bf16x8 ones;
#pragma unroll
  for (int e = 0; e < 8; ++e) ones[e] = (short)0x3F80;

  __syncthreads();   // one-time mask + prologue DMA complete (full drain, once)

  for (int s = 0; s < 8; ++s) {
    if (s) {
      asm volatile("s_waitcnt vmcnt(0)" ::: "memory");  // stage(s) landed
      __builtin_amdgcn_s_barrier();                     // visible to all waves
      __builtin_amdgcn_sched_barrier(0);
    }
    const int slot = s & 1;
    if (s < 7) {
#pragma unroll
      for (int wi = 0; wi < 4; ++wi)
        gload16(WhTf + ((fbase + (s + 1) * 4 + wi) << 9) + lane * 8,
                &abuf[slot ^ 1][wi][w][lane * 8]);
    }
#pragma unroll
    for (int wi = 0; wi < 4; ++wi) {
      const int jt = s * 4 + wi;
      bf16x8 af[4];
#pragma unroll
      for (int ft = 0; ft < 4; ++ft)
        af[ft] = *(const bf16x8*)&abuf[slot][wi][ft][lane * 8];
      const f32x4* __restrict__ ejp = (const f32x4*)(ejbase + jt * 64);
      const f32x4 q0 = ejp[0], q1 = ejp[1], q2 = ejp[2], q3 = ejp[3];
      const unsigned mb = mldsT[jt][w * 16 + jp] >> (rg * 8);

      bf16x8 p;
#pragma unroll
      for (int e = 0; e < 8; ++e) {
        const f32x4 qq = (e < 2) ? q0 : (e < 4) ? q1 : (e < 6) ? q2 : q3;
        const float E1j = qq[(e & 1) * 2];
        const float E2j = qq[(e & 1) * 2 + 1];
        float pv = fmaxf(E1i * E1j, E2i * E2j);   // == exp2(leaky(score))
        pv = ((mb >> e) & 1u) ? pv : 0.0f;        // adjacency mask
        p[e] = bf16s(pv);
      }
      accd = __builtin_amdgcn_mfma_f32_16x16x32_bf16(ones, p, accd, 0, 0, 0);
#pragma unroll
      for (int ft = 0; ft < 4; ++ft)
        acc[ft] = __builtin_amdgcn_mfma_f32_16x16x32_bf16(af[ft], p, acc[ft], 0, 0, 0);
    }
  }

  // store partials: acc[ft][r] = D[f=ft*16+rg*4+r][i = i0+w*16+jp]
  const size_t obase = (((size_t)(c * 4 + b) * NN) + i0 + w * 16 + jp) * 64;
#pragma unroll
  for (int ft = 0; ft < 4; ++ft) {
    s16x4 pk;
#pragma unroll
    for (int r = 0; r < 4; ++r) pk[r] = bf16s(acc[ft][r]);
    *(s16x4*)(Pp + obase + ft * 16 + rg * 4) = pk;
  }
  if (rg == 0)
    lsp[(size_t)(c * 4 + b) * NN + i0 + w * 16 + jp] = accd[0];
}

// ---------------------------------------------------------------------------
// Kernel 3: combine chunk partials, normalize, BatchNorm + residual + ELU.
// Grid 2048 (2 nodes/block); wave = batch.
// ---------------------------------------------------------------------------
__global__ __launch_bounds__(256)
void k_bn(const float* __restrict__ h, const unsigned short* __restrict__ Pp,
          const float* __restrict__ lsp, const float* __restrict__ gamma,
          const float* __restrict__ beta, float* __restrict__ out) {
  __shared__ float bnp[2][4][2];
  const int t = threadIdx.x;
  const int w = t >> 6, lane = t & 63;   // w = batch
  const int i0 = blockIdx.x * 2;
  float x[2];
#pragma unroll
  for (int ii = 0; ii < 2; ++ii) {
    const int i = i0 + ii;
    float xv = 0.f, lt = 0.f;
#pragma unroll
    for (int cc = 0; cc < 4; ++cc) {
      xv += bf2f(Pp[((size_t)(cc * 4 + w) * NN + i) * 64 + lane]);
      lt += lsp[(size_t)(cc * 4 + w) * NN + i];
    }
    xv /= lt;
    x[ii] = xv;
    float s1 = xv, s2 = xv * xv;
#pragma unroll
    for (int m = 32; m; m >>= 1) { s1 += __shfl_xor(s1, m); s2 += __shfl_xor(s2, m); }
    if (lane == 0) { bnp[ii][w][0] = s1; bnp[ii][w][1] = s2; }
  }
  __syncthreads();
#pragma unroll
  for (int ii = 0; ii < 2; ++ii) {
    const float t1 = bnp[ii][0][0] + bnp[ii][1][0] + bnp[ii][2][0] + bnp[ii][3][0];
    const float t2 = bnp[ii][0][1] + bnp[ii][1][1] + bnp[ii][2][1] + bnp[ii][3][1];
    const float mean = t1 * (1.f / 256.f);
    const float var  = t2 * (1.f / 256.f) - mean * mean;
    const float sc = gamma[i0 + ii] * rsqrtf(var + 1e-5f);
    const float bt = beta[i0 + ii];
    const size_t off = (((size_t)(w * NN + i0 + ii)) << 6) + lane;
    float o = sc * (x[ii] - mean) + bt + h[off];
    o = o > 0.f ? o : exp2_fast(o * LOG2E) - 1.f;
    out[off] = o;
  }
}

// ---------------------------------------------------------------------------
extern "C" void kernel_launch(void* const* d_in, const int* in_sizes, int n_in,
                              void* d_out, int out_size, void* d_ws, size_t ws_size,
                              hipStream_t stream) {
  (void)in_sizes; (void)n_in; (void)out_size; (void)ws_size;
  const float* h     = (const float*)d_in[0];
  const int*   adj   = (const int*)d_in[1];
  const float* W     = (const float*)d_in[2];
  const float* a     = (const float*)d_in[3];
  const float* gamma = (const float*)d_in[4];
  const float* beta  = (const float*)d_in[5];
  float* out = (float*)d_out;

  char* ws = (char*)d_ws;
  unsigned short* WhTf = (unsigned short*)ws;                    // 2 MB @ 0
  unsigned* bits = (unsigned*)(ws + (2u << 20));                 // 2 MB @ 2M
  float2* Eit = (float2*)(ws + (4u << 20));                      // 128 KB
  float2* Ejt = (float2*)(ws + (4u << 20) + (128u << 10));       // 128 KB
  float* lsp = (float*)(ws + (4u << 20) + (256u << 10));         // 256 KB
  unsigned short* Pp = (unsigned short*)(ws + (4u << 20) + (512u << 10)); // 8 MB

  k_prep<<<2560, 256, 0, stream>>>(h, W, a, adj, WhTf, Eit, Ejt, bits);
  k_gat<<<1024, 256, 0, stream>>>(bits, WhTf, Eit, (const float*)Ejt, Pp, lsp);
  k_bn<<<2048, 256, 0, stream>>>(h, Pp, lsp, gamma, beta, out);
}

// Round 13
// 52.101 us; speedup vs baseline: 1.1668x; 1.1668x over previous
//
#include <hip/hip_runtime.h>
#include <hip/hip_fp16.h>
#include <math.h>

#define NN 4096
// (1/64) * log2(e)  -- folds 1/sqrt(N) and exp->exp2 conversion
#define SCL 0.022542110013890054f
#define LOG2E 1.4426950408889634f

typedef __attribute__((ext_vector_type(8))) _Float16 f16x8;
typedef __attribute__((ext_vector_type(2))) _Float16 f16x2;
typedef __attribute__((ext_vector_type(4))) float f32x4;
typedef __attribute__((ext_vector_type(4))) short s16x4;

__device__ __forceinline__ float exp2_fast(float x) {
  float r; asm("v_exp_f32 %0, %1" : "=v"(r) : "v"(x)); return r;
}
__device__ __forceinline__ unsigned short h16(float x) {
  _Float16 h = (_Float16)x; return *(unsigned short*)&h;
}

// ---------------------------------------------------------------------------
// Kernel 1 (fused by block range):
//   blocks [0,2048):    Wh = h@W -> fragment-major WhTf (f16);
//                       Ei1/Ei2 = dup-half2(2^w1s, 2^0.2w1s) per row;
//                       Ej1/Ej2 = paired-half2 over row pairs (for j role).
//   blocks [2048,3072): adj -> bits[i][g] via coalesced dword-ballot,
//                       1 row/wave, lane l latches word l (validated r11).
// ---------------------------------------------------------------------------
__global__ __launch_bounds__(256)
void k_prep(const float* __restrict__ h, const float* __restrict__ W,
            const float* __restrict__ a, const int* __restrict__ adj,
            unsigned short* __restrict__ WhTf, unsigned* __restrict__ Ei1,
            unsigned* __restrict__ Ei2, unsigned* __restrict__ Ej1,
            unsigned* __restrict__ Ej2, unsigned* __restrict__ bits) {
  __shared__ float sW[4096];
  __shared__ unsigned short T[64][8];
  const int t = threadIdx.x;
  const int bi = blockIdx.x;
  if (bi >= 2048) {
    const int w = t >> 6, lane = t & 63;
    const int r = (bi - 2048) * 4 + w;           // one row per wave
    const int kq = lane >> 1, hi = lane & 1;
#pragma unroll
    for (int half = 0; half < 2; ++half) {
      const int* __restrict__ src = adj + ((size_t)r << 12) + half * 2048;
      unsigned myw = 0;
      for (int k = 0; k < 32; ++k) {
        unsigned long long m = __ballot(src[k * 64 + lane] != 0);
        unsigned lohi = hi ? (unsigned)(m >> 32) : (unsigned)m;
        myw = (kq == k) ? lohi : myw;
      }
      bits[((size_t)r << 7) + half * 64 + lane] = myw;
    }
    return;
  }
  // ---- Wh path: 8 rows (same batch) per block ----
#pragma unroll
  for (int i = 0; i < 16; ++i) sW[i * 256 + t] = W[i * 256 + t];
  __syncthreads();
  const int wv = t >> 6, lane = t & 63;
  const float a1 = a[lane], a2 = a[64 + lane];
  const int row0 = bi * 8;
  const int q0 = row0 + wv * 2;                  // this wave's even row
  float w1v[2], w2v[2];
  for (int r = 0; r < 2; ++r) {
    const int row = q0 + r;
    const float* hr = h + (size_t)row * 64;
    float acc = 0.f;
#pragma unroll
    for (int k = 0; k < 64; ++k) acc = fmaf(hr[k], sW[k * 64 + lane], acc);
    T[lane][wv * 2 + r] = h16(acc);
    float r1 = acc * a1, r2 = acc * a2;
#pragma unroll
    for (int sft = 32; sft; sft >>= 1) { r1 += __shfl_xor(r1, sft); r2 += __shfl_xor(r2, sft); }
    w1v[r] = r1 * SCL; w2v[r] = r2 * SCL;
  }
  if (lane == 0) {
#pragma unroll
    for (int r = 0; r < 2; ++r) {
      unsigned u1 = h16(exp2_fast(w1v[r]));
      unsigned u2 = h16(exp2_fast(0.2f * w1v[r]));
      Ei1[q0 + r] = u1 | (u1 << 16);
      Ei2[q0 + r] = u2 | (u2 << 16);
    }
    Ej1[q0 >> 1] = (unsigned)h16(exp2_fast(w2v[0])) |
                   ((unsigned)h16(exp2_fast(w2v[1])) << 16);
    Ej2[q0 >> 1] = (unsigned)h16(exp2_fast(0.2f * w2v[0])) |
                   ((unsigned)h16(exp2_fast(0.2f * w2v[1])) << 16);
  }
  __syncthreads();
  // fragment-major store (validated layout, f16 values): (b, ft, g, lane, e)
  // holds Wh[n = g*32 + rg*8 + e][f = ft*16 + jp],  lane = rg*16 + jp.
  const int f = t >> 2, jp4 = t & 3;
  const int b = row0 >> 12, n0 = row0 & 4095;
  const int g32 = n0 >> 5, rgq = (n0 >> 3) & 3;
  unsigned v = *(unsigned*)&T[f][jp4 * 2];
  unsigned short* dst = WhTf +
      ((((size_t)(b * 4 + (f >> 4)) << 7) + g32) << 9) +
      ((rgq * 16 + (f & 15)) << 3) + jp4 * 2;
  *(unsigned*)dst = v;
}

// ---------------------------------------------------------------------------
// Kernel 2: masked-softmax attention partials via f16 MFMA, big-tile waves.
// Grid 512 = 8 chunks x 4 b x 16 i-blocks (256 i). Block 256 thr = 4 waves;
// wave w owns i-rows [i0b+64w, +64) (4 islices), sweeps the chunk's 16
// windows. NO staging, NO barriers in main loop: A-frags stream global->VGPR
// (L2-resident, L1-shared across the block's 4 waves, reused over 4 islices);
// Ej pairs via 2 x b128 broadcast loads; masks from a one-time LDS tile.
// P pair = pk_max(pk_mul(Ei1,Ej1), pk_mul(Ei2,Ej2)) & bitmask-expand  (exact
// rank-1 max factorization of exp2(leaky(s)), f16 packed math).
// 20 MFMA/window (16 PV + 4 ones-denominator). acc = 64 VGPR.
// ---------------------------------------------------------------------------
__global__ __launch_bounds__(256, 2)
void k_gat(const unsigned* __restrict__ bits,
           const unsigned short* __restrict__ WhTf,
           const unsigned* __restrict__ Ei1, const unsigned* __restrict__ Ei2,
           const unsigned* __restrict__ Ej1, const unsigned* __restrict__ Ej2,
           unsigned short* __restrict__ Pp, float* __restrict__ lsp) {
  __shared__ unsigned mlds[256][17];   // [row][window] mask words, 17.4 KB

  const int t = threadIdx.x;
  const int w = t >> 6, lane = t & 63;
  const int jp = lane & 15, rg = lane >> 4;
  const int bid = blockIdx.x;
  const int c = bid >> 6;              // 0..7 chunk
  const int b = (bid >> 4) & 3;
  const int i0b = (bid & 15) * 256;    // block row base
  const int i0 = i0b + w * 64;         // wave row base
  const int g0 = c * 16;

  // one-time: mask tile (coalesced: 16 rows x 16 words per pass)
#pragma unroll
  for (int pass = 0; pass < 16; ++pass) {
    const int row = pass * 16 + (t >> 4);
    mlds[row][t & 15] = bits[((size_t)(i0b + row) << 7) + g0 + (t & 15)];
  }

  unsigned ei1u[4], ei2u[4];
#pragma unroll
  for (int il = 0; il < 4; ++il) {
    ei1u[il] = Ei1[b * NN + i0 + il * 16 + jp];
    ei2u[il] = Ei2[b * NN + i0 + il * 16 + jp];
  }
  const unsigned short* __restrict__ abase =
      WhTf + (((size_t)(b * 4) << 7) + g0) * 512 + lane * 8;
  const unsigned* __restrict__ ej1b = Ej1 + (b << 11) + (g0 << 4) + (rg << 2);
  const unsigned* __restrict__ ej2b = Ej2 + (b << 11) + (g0 << 4) + (rg << 2);

  f32x4 acc[4][4];                     // [islice][ft]
  f32x4 accd[4];
#pragma unroll
  for (int il = 0; il < 4; ++il) {
    accd[il] = (f32x4){0.f, 0.f, 0.f, 0.f};
#pragma unroll
    for (int ft = 0; ft < 4; ++ft) acc[il][ft] = (f32x4){0.f, 0.f, 0.f, 0.f};
  }
  f16x8 ones;
#pragma unroll
  for (int e = 0; e < 8; ++e) ones[e] = (_Float16)1.0f;

  __syncthreads();   // mask tile ready; no barriers below

#pragma unroll 4
  for (int jt = 0; jt < 16; ++jt) {
    const f16x8 af0 = *(const f16x8*)(abase + (0 * 128 + jt) * 512);
    const f16x8 af1 = *(const f16x8*)(abase + (1 * 128 + jt) * 512);
    const f16x8 af2 = *(const f16x8*)(abase + (2 * 128 + jt) * 512);
    const f16x8 af3 = *(const f16x8*)(abase + (3 * 128 + jt) * 512);
    const uint4 e1p = *(const uint4*)(ej1b + jt * 16);
    const uint4 e2p = *(const uint4*)(ej2b + jt * 16);
    const unsigned e1a[4] = {e1p.x, e1p.y, e1p.z, e1p.w};
    const unsigned e2a[4] = {e2p.x, e2p.y, e2p.z, e2p.w};

    f16x8 pf[4];
#pragma unroll
    for (int il = 0; il < 4; ++il) {
      const unsigned mb = mlds[w * 64 + il * 16 + jp][jt] >> (rg * 8);
      const f16x2 x1 = *(const f16x2*)&ei1u[il];
      const f16x2 x2 = *(const f16x2*)&ei2u[il];
      unsigned pw[4];
#pragma unroll
      for (int p4 = 0; p4 < 4; ++p4) {
        f16x2 c1 = x1 * (*(const f16x2*)&e1a[p4]);
        f16x2 c2 = x2 * (*(const f16x2*)&e2a[p4]);
        f16x2 mx = __builtin_elementwise_max(c1, c2);  // exp2(leaky(s)) pair
        unsigned mexp = (((mb >> (2 * p4)) & 1u) ? 0xFFFFu : 0u) |
                        (((mb >> (2 * p4 + 1)) & 1u) ? 0xFFFF0000u : 0u);
        pw[p4] = (*(unsigned*)&mx) & mexp;     // adjacency mask -> +0.0
      }
      pf[il] = *(f16x8*)pw;
    }
#pragma unroll
    for (int il = 0; il < 4; ++il) {
      accd[il] = __builtin_amdgcn_mfma_f32_16x16x32_f16(ones, pf[il], accd[il], 0, 0, 0);
      acc[il][0] = __builtin_amdgcn_mfma_f32_16x16x32_f16(af0, pf[il], acc[il][0], 0, 0, 0);
      acc[il][1] = __builtin_amdgcn_mfma_f32_16x16x32_f16(af1, pf[il], acc[il][1], 0, 0, 0);
      acc[il][2] = __builtin_amdgcn_mfma_f32_16x16x32_f16(af2, pf[il], acc[il][2], 0, 0, 0);
      acc[il][3] = __builtin_amdgcn_mfma_f32_16x16x32_f16(af3, pf[il], acc[il][3], 0, 0, 0);
    }
  }

  // denominator partials (all D rows identical; take reg 0 at rg==0)
  if (rg == 0) {
#pragma unroll
    for (int il = 0; il < 4; ++il)
      lsp[(size_t)(c * 4 + b) * NN + i0 + il * 16 + jp] = accd[il][0];
  }
  // unnormalized f16 partials: acc[il][ft][r] = D[f=ft*16+rg*4+r][i=i0+il*16+jp]
  const size_t pbase = (((size_t)(c * 4 + b)) * NN + i0) * 64;
#pragma unroll
  for (int il = 0; il < 4; ++il)
#pragma unroll
    for (int ft = 0; ft < 4; ++ft) {
      s16x4 pk;
#pragma unroll
      for (int r = 0; r < 4; ++r) pk[r] = (short)h16(acc[il][ft][r]);
      *(s16x4*)(Pp + pbase + (size_t)(il * 16 + jp) * 64 + ft * 16 + rg * 4) = pk;
    }
}

// ---------------------------------------------------------------------------
// Kernel 3: combine 8 chunk partials, normalize, BatchNorm + residual + ELU.
// Grid 2048 (2 nodes/block); wave = batch.
// ---------------------------------------------------------------------------
__global__ __launch_bounds__(256)
void k_bn(const float* __restrict__ h, const unsigned short* __restrict__ Pp,
          const float* __restrict__ lsp, const float* __restrict__ gamma,
          const float* __restrict__ beta, float* __restrict__ out) {
  __shared__ float bnp[2][4][2];
  const int t = threadIdx.x;
  const int w = t >> 6, lane = t & 63;   // w = batch
  const int i0 = blockIdx.x * 2;
  float x[2];
#pragma unroll
  for (int ii = 0; ii < 2; ++ii) {
    const int i = i0 + ii;
    float xv = 0.f, lt = 0.f;
#pragma unroll
    for (int cc = 0; cc < 8; ++cc) {
      xv += (float)(*(const _Float16*)(Pp + ((size_t)(cc * 4 + w) * NN + i) * 64 + lane));
      lt += lsp[(size_t)(cc * 4 + w) * NN + i];
    }
    xv /= lt;
    x[ii] = xv;
    float s1 = xv, s2 = xv * xv;
#pragma unroll
    for (int m = 32; m; m >>= 1) { s1 += __shfl_xor(s1, m); s2 += __shfl_xor(s2, m); }
    if (lane == 0) { bnp[ii][w][0] = s1; bnp[ii][w][1] = s2; }
  }
  __syncthreads();
#pragma unroll
  for (int ii = 0; ii < 2; ++ii) {
    const float t1 = bnp[ii][0][0] + bnp[ii][1][0] + bnp[ii][2][0] + bnp[ii][3][0];
    const float t2 = bnp[ii][0][1] + bnp[ii][1][1] + bnp[ii][2][1] + bnp[ii][3][1];
    const float mean = t1 * (1.f / 256.f);
    const float var  = t2 * (1.f / 256.f) - mean * mean;
    const float sc = gamma[i0 + ii] * rsqrtf(var + 1e-5f);
    const float bt = beta[i0 + ii];
    const size_t off = (((size_t)(w * NN + i0 + ii)) << 6) + lane;
    float o = sc * (x[ii] - mean) + bt + h[off];
    o = o > 0.f ? o : exp2_fast(o * LOG2E) - 1.f;
    out[off] = o;
  }
}

// ---------------------------------------------------------------------------
extern "C" void kernel_launch(void* const* d_in, const int* in_sizes, int n_in,
                              void* d_out, int out_size, void* d_ws, size_t ws_size,
                              hipStream_t stream) {
  (void)in_sizes; (void)n_in; (void)out_size; (void)ws_size;
  const float* h     = (const float*)d_in[0];
  const int*   adj   = (const int*)d_in[1];
  const float* W     = (const float*)d_in[2];
  const float* a     = (const float*)d_in[3];
  const float* gamma = (const float*)d_in[4];
  const float* beta  = (const float*)d_in[5];
  float* out = (float*)d_out;

  char* ws = (char*)d_ws;
  unsigned short* WhTf = (unsigned short*)ws;                 // 2 MB @ 0
  unsigned* bits = (unsigned*)(ws + (2u << 20));              // 2 MB @ 2M
  unsigned* Ei1 = (unsigned*)(ws + (4u << 20));               // 64 KB
  unsigned* Ei2 = (unsigned*)(ws + (4u << 20) + (64u << 10)); // 64 KB
  unsigned* Ej1 = (unsigned*)(ws + (4u << 20) + (128u << 10)); // 32 KB
  unsigned* Ej2 = (unsigned*)(ws + (4u << 20) + (160u << 10)); // 32 KB
  float* lsp = (float*)(ws + (4u << 20) + (192u << 10));      // 512 KB
  unsigned short* Pp = (unsigned short*)(ws + (5u << 20));    // 16.8 MB

  k_prep<<<3072, 256, 0, stream>>>(h, W, a, adj, WhTf, Ei1, Ei2, Ej1, Ej2, bits);
  k_gat<<<512, 256, 0, stream>>>(bits, WhTf, Ei1, Ei2, Ej1, Ej2, Pp, lsp);
  k_bn<<<2048, 256, 0, stream>>>(h, Pp, lsp, gamma, beta, out);
}